// Round 1
// baseline (1028.537 us; speedup 1.0000x reference)
//
#include <hip/hip_runtime.h>

#define BB 2
#define LL 1536
#define DD 1024
#define HH 16
#define HDD 64
#define PP 1024

typedef __attribute__((ext_vector_type(8))) __bf16 bf16x8;
typedef __attribute__((ext_vector_type(4))) float f32x4;
typedef __attribute__((ext_vector_type(8))) unsigned short u16x8;

__device__ __forceinline__ float b2f(unsigned short u) {
  unsigned int x = ((unsigned int)u) << 16;
  return __builtin_bit_cast(float, x);
}
__device__ __forceinline__ unsigned short f2b(float f) {
  unsigned int x = __builtin_bit_cast(unsigned int, f);
  unsigned int r = (x + 0x7FFFu + ((x >> 16) & 1u)) >> 16;
  return (unsigned short)r;
}

// ---------------- fp32 tiled GEMM: C[M,1024] = A[M,1024] @ W[1024,1024] + b ----
// 128x128 tile, BK=16, 256 threads, 8x8 per thread.
template <bool BF16OUT>
__device__ __forceinline__ void gemm128(const float* __restrict__ A,
                                        const float* __restrict__ W,
                                        const float* __restrict__ bias,
                                        void* __restrict__ Cout, float scale) {
  __shared__ float As[16][128];
  __shared__ float Bs[16][128];
  const int t = threadIdx.x;
  const int tr = t >> 4, tc = t & 15;
  const int m0 = blockIdx.y * 128, n0 = blockIdx.x * 128;
  const int arow = t >> 1, acol = (t & 1) * 8;
  const int brow = t >> 5, bcol = (t & 31) * 4;

  float acc[8][8];
#pragma unroll
  for (int i = 0; i < 8; ++i)
#pragma unroll
    for (int j = 0; j < 8; ++j) acc[i][j] = 0.f;

  for (int k0 = 0; k0 < 1024; k0 += 16) {
    float4 av0 = *(const float4*)&A[(size_t)(m0 + arow) * 1024 + k0 + acol];
    float4 av1 = *(const float4*)&A[(size_t)(m0 + arow) * 1024 + k0 + acol + 4];
    float4 bv0 = *(const float4*)&W[(size_t)(k0 + brow) * 1024 + n0 + bcol];
    float4 bv1 = *(const float4*)&W[(size_t)(k0 + brow + 8) * 1024 + n0 + bcol];
    __syncthreads();  // protect previous iteration's LDS readers
    As[acol + 0][arow] = av0.x;
    As[acol + 1][arow] = av0.y;
    As[acol + 2][arow] = av0.z;
    As[acol + 3][arow] = av0.w;
    As[acol + 4][arow] = av1.x;
    As[acol + 5][arow] = av1.y;
    As[acol + 6][arow] = av1.z;
    As[acol + 7][arow] = av1.w;
    *(float4*)&Bs[brow][bcol] = bv0;
    *(float4*)&Bs[brow + 8][bcol] = bv1;
    __syncthreads();
#pragma unroll
    for (int kk = 0; kk < 16; ++kk) {
      float4 a0 = *(float4*)&As[kk][tr * 8];
      float4 a1 = *(float4*)&As[kk][tr * 8 + 4];
      float4 b0 = *(float4*)&Bs[kk][tc * 8];
      float4 b1 = *(float4*)&Bs[kk][tc * 8 + 4];
      float aa[8] = {a0.x, a0.y, a0.z, a0.w, a1.x, a1.y, a1.z, a1.w};
      float bb[8] = {b0.x, b0.y, b0.z, b0.w, b1.x, b1.y, b1.z, b1.w};
#pragma unroll
      for (int i = 0; i < 8; ++i)
#pragma unroll
        for (int j = 0; j < 8; ++j) acc[i][j] += aa[i] * bb[j];
    }
  }
#pragma unroll
  for (int i = 0; i < 8; ++i) {
    const int m = m0 + tr * 8 + i;
    const int n = n0 + tc * 8;
    float o[8];
#pragma unroll
    for (int j = 0; j < 8; ++j) o[j] = (acc[i][j] + bias[n + j]) * scale;
    if constexpr (BF16OUT) {
      uint4 u;
      u.x = (unsigned int)f2b(o[0]) | ((unsigned int)f2b(o[1]) << 16);
      u.y = (unsigned int)f2b(o[2]) | ((unsigned int)f2b(o[3]) << 16);
      u.z = (unsigned int)f2b(o[4]) | ((unsigned int)f2b(o[5]) << 16);
      u.w = (unsigned int)f2b(o[6]) | ((unsigned int)f2b(o[7]) << 16);
      *(uint4*)((unsigned short*)Cout + (size_t)m * 1024 + n) = u;
    } else {
      float* Cf = (float*)Cout;
      *(float4*)&Cf[(size_t)m * 1024 + n] = make_float4(o[0], o[1], o[2], o[3]);
      *(float4*)&Cf[(size_t)m * 1024 + n + 4] =
          make_float4(o[4], o[5], o[6], o[7]);
    }
  }
}

// QKV: blockIdx.z selects Q (scale 1/sqrt(64) folded in), K, V; bf16 outputs.
__global__ __launch_bounds__(256) void qkv_gemm(
    const float* __restrict__ hs, const float* __restrict__ Wq,
    const float* __restrict__ bq, const float* __restrict__ Wk,
    const float* __restrict__ bk, const float* __restrict__ Wv,
    const float* __restrict__ bv, unsigned short* __restrict__ Qb,
    unsigned short* __restrict__ Kb, unsigned short* __restrict__ Vb) {
  const float* W;
  const float* bias;
  unsigned short* O;
  float scale = 1.0f;
  if (blockIdx.z == 0) {
    W = Wq; bias = bq; O = Qb; scale = 0.125f;  // 1/sqrt(HD)
  } else if (blockIdx.z == 1) {
    W = Wk; bias = bk; O = Kb;
  } else {
    W = Wv; bias = bv; O = Vb;
  }
  gemm128<true>(hs, W, bias, O, scale);
}

__global__ __launch_bounds__(256) void out_gemm(const float* __restrict__ ctx,
                                                const float* __restrict__ Wo,
                                                const float* __restrict__ bo,
                                                float* __restrict__ out) {
  gemm128<false>(ctx, Wo, bo, out, 1.0f);
}

// ---------------- fused attention: scores -> softmax -> 3x diffusion -> PV ----
// One block per (b, h, 16-row q tile). p rows live in LDS as bf16.
__global__ __launch_bounds__(256) void attn_kernel(
    const unsigned short* __restrict__ Qb, const unsigned short* __restrict__ Kb,
    const unsigned short* __restrict__ Vb, const int* __restrict__ mask,
    const float* __restrict__ kernel_w, float* __restrict__ ctx) {
  __shared__ unsigned short p_b[16][1536];  // 48 KB
  __shared__ unsigned short Qs[16][64];     // 2 KB
  __shared__ unsigned short KVs[64][64];    // 8 KB (K then V staging)
  __shared__ unsigned short kvs[1536];      // 3 KB key-valid flags
  __shared__ float red_m[4][16];
  __shared__ float red_s[4][16];

  const int t = threadIdx.x;
  const int lane = t & 63;
  const int w = t >> 6;        // wave id 0..3
  const int quad = lane >> 4;  // 0..3
  const int lc = lane & 15;
  const int b = blockIdx.z, h = blockIdx.y;
  const int q0 = blockIdx.x * 16;

  if (t < 128) {
    int row = t >> 3, c8 = (t & 7) * 8;
    *(uint4*)&Qs[row][c8] =
        *(const uint4*)&Qb[((size_t)(b * LL + q0 + row)) * PP + h * HDD + c8];
  }
  for (int i = t; i < LL; i += 256) kvs[i] = (mask[b * LL + i] > 0) ? 1 : 0;
  __syncthreads();

  // ---- phase 1: scores via MFMA. Wave w owns key columns g*64 + w*16 + lc.
  float sc[24][4];
  bf16x8 qa0 = __builtin_bit_cast(bf16x8, *(const uint4*)&Qs[lc][quad * 8]);
  bf16x8 qa1 = __builtin_bit_cast(bf16x8, *(const uint4*)&Qs[lc][32 + quad * 8]);
#pragma unroll
  for (int g = 0; g < 24; ++g) {
    const unsigned short* Ksrc = Kb + ((size_t)(b * LL + g * 64)) * PP + h * HDD;
#pragma unroll
    for (int j = 0; j < 2; ++j) {
      int idx = t + j * 256;
      int row = idx >> 3, c8 = (idx & 7) * 8;
      *(uint4*)&KVs[row][c8] = *(const uint4*)&Ksrc[(size_t)row * PP + c8];
    }
    __syncthreads();
    bf16x8 kb0 =
        __builtin_bit_cast(bf16x8, *(const uint4*)&KVs[w * 16 + lc][quad * 8]);
    bf16x8 kb1 = __builtin_bit_cast(
        bf16x8, *(const uint4*)&KVs[w * 16 + lc][32 + quad * 8]);
    f32x4 acc = {0.f, 0.f, 0.f, 0.f};
    acc = __builtin_amdgcn_mfma_f32_16x16x32_bf16(qa0, kb0, acc, 0, 0, 0);
    acc = __builtin_amdgcn_mfma_f32_16x16x32_bf16(qa1, kb1, acc, 0, 0, 0);
    sc[g][0] = acc[0];
    sc[g][1] = acc[1];
    sc[g][2] = acc[2];
    sc[g][3] = acc[3];
    __syncthreads();
  }

  // ---- phase 2: masked softmax (rows q = quad*4+r, cols g*64+w*16+lc)
  unsigned int mbits = 0;
#pragma unroll
  for (int g = 0; g < 24; ++g)
    if (kvs[g * 64 + w * 16 + lc]) mbits |= (1u << g);

  float inv[4];
  {
    float mrow[4], srow[4];
#pragma unroll
    for (int r = 0; r < 4; ++r) {
      float m = -1e30f;
#pragma unroll
      for (int g = 0; g < 24; ++g)
        if ((mbits >> g) & 1u) m = fmaxf(m, sc[g][r]);
#pragma unroll
      for (int off = 1; off < 16; off <<= 1)
        m = fmaxf(m, __shfl_xor(m, off, 64));
      mrow[r] = m;
    }
    if (lc == 0) {
#pragma unroll
      for (int r = 0; r < 4; ++r) red_m[w][quad * 4 + r] = mrow[r];
    }
    __syncthreads();
#pragma unroll
    for (int r = 0; r < 4; ++r) {
      float m = red_m[0][quad * 4 + r];
      m = fmaxf(m, red_m[1][quad * 4 + r]);
      m = fmaxf(m, red_m[2][quad * 4 + r]);
      m = fmaxf(m, red_m[3][quad * 4 + r]);
      mrow[r] = m;
    }
#pragma unroll
    for (int r = 0; r < 4; ++r) {
      float s = 0.f;
#pragma unroll
      for (int g = 0; g < 24; ++g) {
        float e = ((mbits >> g) & 1u) ? __expf(sc[g][r] - mrow[r]) : 0.f;
        sc[g][r] = e;
        s += e;
      }
#pragma unroll
      for (int off = 1; off < 16; off <<= 1) s += __shfl_xor(s, off, 64);
      srow[r] = s;
    }
    if (lc == 0) {
#pragma unroll
      for (int r = 0; r < 4; ++r) red_s[w][quad * 4 + r] = srow[r];
    }
    __syncthreads();
#pragma unroll
    for (int r = 0; r < 4; ++r) {
      float tot = red_s[0][quad * 4 + r] + red_s[1][quad * 4 + r] +
                  red_s[2][quad * 4 + r] + red_s[3][quad * 4 + r];
      inv[r] = 1.f / tot;
    }
  }
#pragma unroll
  for (int g = 0; g < 24; ++g)
#pragma unroll
    for (int r = 0; r < 4; ++r)
      p_b[quad * 4 + r][g * 64 + w * 16 + lc] = f2b(sc[g][r] * inv[r]);
  __syncthreads();

  // ---- phase 3: 3 diffusion steps. Wave w owns rows 4w..4w+3; lane owns
  // 24 contiguous keys. wr[d] multiplies p[k-d]; ref weight = w_sm[4-d].
  float wr[5];
  {
    float k0 = kernel_w[0], k1 = kernel_w[1], k2 = kernel_w[2],
          k3 = kernel_w[3], k4 = kernel_w[4];
    float km = fmaxf(fmaxf(fmaxf(k0, k1), fmaxf(k2, k3)), k4);
    float e0 = __expf(k0 - km), e1 = __expf(k1 - km), e2 = __expf(k2 - km),
          e3 = __expf(k3 - km), e4 = __expf(k4 - km);
    float es = e0 + e1 + e2 + e3 + e4;
    wr[0] = e4 / es;
    wr[1] = e3 / es;
    wr[2] = e2 / es;
    wr[3] = e1 / es;
    wr[4] = e0 / es;
  }
  unsigned int db = 0;
#pragma unroll
  for (int i = 0; i < 24; ++i)
    if (kvs[lane * 24 + i]) db |= (1u << i);

  for (int step = 0; step < 3; ++step) {
#pragma unroll
    for (int rr = 0; rr < 4; ++rr) {
      const int row = w * 4 + rr;
      float pf[28];
      if (lane == 0) {
        pf[0] = pf[1] = pf[2] = pf[3] = 0.f;
      } else {
        uint2 hv = *(const uint2*)&p_b[row][lane * 24 - 4];
        pf[0] = b2f((unsigned short)(hv.x & 0xFFFF));
        pf[1] = b2f((unsigned short)(hv.x >> 16));
        pf[2] = b2f((unsigned short)(hv.y & 0xFFFF));
        pf[3] = b2f((unsigned short)(hv.y >> 16));
      }
#pragma unroll
      for (int c = 0; c < 3; ++c) {
        uint4 v = *(const uint4*)&p_b[row][lane * 24 + c * 8];
        pf[4 + c * 8 + 0] = b2f((unsigned short)(v.x & 0xFFFF));
        pf[4 + c * 8 + 1] = b2f((unsigned short)(v.x >> 16));
        pf[4 + c * 8 + 2] = b2f((unsigned short)(v.y & 0xFFFF));
        pf[4 + c * 8 + 3] = b2f((unsigned short)(v.y >> 16));
        pf[4 + c * 8 + 4] = b2f((unsigned short)(v.z & 0xFFFF));
        pf[4 + c * 8 + 5] = b2f((unsigned short)(v.z >> 16));
        pf[4 + c * 8 + 6] = b2f((unsigned short)(v.w & 0xFFFF));
        pf[4 + c * 8 + 7] = b2f((unsigned short)(v.w >> 16));
      }
      float ps[24];
      float s = 0.f;
#pragma unroll
      for (int i = 0; i < 24; ++i) {
        float v = wr[0] * pf[4 + i] + wr[1] * pf[3 + i] + wr[2] * pf[2 + i] +
                  wr[3] * pf[1 + i] + wr[4] * pf[i];
        v = ((db >> i) & 1u) ? v : 0.f;
        ps[i] = v;
        s += v;
      }
#pragma unroll
      for (int off = 1; off < 64; off <<= 1) s += __shfl_xor(s, off, 64);
      const float pinv = 1.f / (s + 1e-9f);
#pragma unroll
      for (int c = 0; c < 3; ++c) {
        unsigned short ob[8];
#pragma unroll
        for (int j = 0; j < 8; ++j) {
          int i = c * 8 + j;
          float pn = 0.98f * pf[4 + i] + 0.02f * ps[i] * pinv;
          ob[j] = f2b(pn);
        }
        uint4 u;
        u.x = (unsigned int)ob[0] | ((unsigned int)ob[1] << 16);
        u.y = (unsigned int)ob[2] | ((unsigned int)ob[3] << 16);
        u.z = (unsigned int)ob[4] | ((unsigned int)ob[5] << 16);
        u.w = (unsigned int)ob[6] | ((unsigned int)ob[7] << 16);
        *(uint4*)&p_b[row][lane * 24 + c * 8] = u;
      }
    }
  }
  __syncthreads();

  // ---- phase 4: PV via MFMA. Wave w owns hd columns w*16 + lc.
  f32x4 oacc = {0.f, 0.f, 0.f, 0.f};
  for (int g = 0; g < 24; ++g) {
    const unsigned short* Vsrc = Vb + ((size_t)(b * LL + g * 64)) * PP + h * HDD;
#pragma unroll
    for (int j = 0; j < 2; ++j) {
      int idx = t + j * 256;
      int row = idx >> 3, c8 = (idx & 7) * 8;
      *(uint4*)&KVs[row][c8] = *(const uint4*)&Vsrc[(size_t)row * PP + c8];
    }
    __syncthreads();
#pragma unroll
    for (int c = 0; c < 2; ++c) {
      bf16x8 pa = __builtin_bit_cast(
          bf16x8, *(const uint4*)&p_b[lc][g * 64 + c * 32 + quad * 8]);
      u16x8 vv;
#pragma unroll
      for (int j = 0; j < 8; ++j)
        vv[j] = KVs[c * 32 + quad * 8 + j][w * 16 + lc];
      bf16x8 vf = __builtin_bit_cast(bf16x8, vv);
      oacc = __builtin_amdgcn_mfma_f32_16x16x32_bf16(pa, vf, oacc, 0, 0, 0);
    }
    __syncthreads();
  }
#pragma unroll
  for (int r = 0; r < 4; ++r)
    ctx[((size_t)(b * LL + q0 + quad * 4 + r)) * PP + h * HDD + w * 16 + lc] =
        oacc[r];
}

extern "C" void kernel_launch(void* const* d_in, const int* in_sizes, int n_in,
                              void* d_out, int out_size, void* d_ws,
                              size_t ws_size, hipStream_t stream) {
  const float* hs = (const float*)d_in[0];
  const int* mask = (const int*)d_in[1];
  const float* Wq = (const float*)d_in[2];
  const float* bq = (const float*)d_in[3];
  const float* Wk = (const float*)d_in[4];
  const float* bk = (const float*)d_in[5];
  const float* Wv = (const float*)d_in[6];
  const float* bv = (const float*)d_in[7];
  const float* Wo = (const float*)d_in[8];
  const float* bo = (const float*)d_in[9];
  const float* kw = (const float*)d_in[10];

  const size_t NBLP = (size_t)BB * LL * PP;  // 3,145,728 elems
  unsigned short* Qb = (unsigned short*)d_ws;
  unsigned short* Kb = Qb + NBLP;
  unsigned short* Vb = Kb + NBLP;
  float* ctx = (float*)(Vb + NBLP);  // 16B-aligned (offset 18,874,368)

  dim3 blk(256);
  qkv_gemm<<<dim3(8, 24, 3), blk, 0, stream>>>(hs, Wq, bq, Wk, bk, Wv, bv, Qb,
                                               Kb, Vb);
  attn_kernel<<<dim3(96, 16, 2), blk, 0, stream>>>(Qb, Kb, Vb, mask, kw, ctx);
  out_gemm<<<dim3(8, 24, 1), blk, 0, stream>>>(ctx, Wo, bo, (float*)d_out);
}

// Round 2
// 676.155 us; speedup vs baseline: 1.5212x; 1.5212x over previous
//
#include <hip/hip_runtime.h>

#define BB 2
#define LL 1536
#define DD 1024
#define HH 16
#define HDD 64
#define PP 1024
#define PBS 1544  // p_b row stride in shorts: 16B-aligned, row step = 4 banks

typedef __attribute__((ext_vector_type(8))) __bf16 bf16x8;
typedef __attribute__((ext_vector_type(4))) float f32x4;

__device__ __forceinline__ float b2f(unsigned short u) {
  unsigned int x = ((unsigned int)u) << 16;
  return __builtin_bit_cast(float, x);
}
__device__ __forceinline__ unsigned short f2b(float f) {
  unsigned int x = __builtin_bit_cast(unsigned int, f);
  unsigned int r = (x + 0x7FFFu + ((x >> 16) & 1u)) >> 16;
  return (unsigned short)r;
}
__device__ __forceinline__ bf16x8 ldb8(const unsigned short* p) {
  return __builtin_bit_cast(bf16x8, *(const uint4*)p);
}

// ---------------- fp32 tiled GEMM: C[M,1024] = A[M,1024] @ W[1024,1024] + b ----
// 128x128 tile, BK=16, 256 threads, 8x8 per thread.
// MODE 0: fp32 out. MODE 1: bf16 out (row-major). MODE 2: bf16 out, V-transposed
// layout VT[b][h][hd][l] (for direct-global MFMA B-frags in attention PV).
template <int MODE>
__device__ __forceinline__ void gemm128(const float* __restrict__ A,
                                        const float* __restrict__ W,
                                        const float* __restrict__ bias,
                                        void* __restrict__ Cout, float scale) {
  __shared__ float As[16][128];
  __shared__ float Bs[16][128];
  const int t = threadIdx.x;
  const int tr = t >> 4, tc = t & 15;
  const int m0 = blockIdx.y * 128, n0 = blockIdx.x * 128;
  const int arow = t >> 1, acol = (t & 1) * 8;
  const int brow = t >> 5, bcol = (t & 31) * 4;

  float acc[8][8];
#pragma unroll
  for (int i = 0; i < 8; ++i)
#pragma unroll
    for (int j = 0; j < 8; ++j) acc[i][j] = 0.f;

  for (int k0 = 0; k0 < 1024; k0 += 16) {
    float4 av0 = *(const float4*)&A[(size_t)(m0 + arow) * 1024 + k0 + acol];
    float4 av1 = *(const float4*)&A[(size_t)(m0 + arow) * 1024 + k0 + acol + 4];
    float4 bv0 = *(const float4*)&W[(size_t)(k0 + brow) * 1024 + n0 + bcol];
    float4 bv1 = *(const float4*)&W[(size_t)(k0 + brow + 8) * 1024 + n0 + bcol];
    __syncthreads();  // protect previous iteration's LDS readers
    As[acol + 0][arow] = av0.x;
    As[acol + 1][arow] = av0.y;
    As[acol + 2][arow] = av0.z;
    As[acol + 3][arow] = av0.w;
    As[acol + 4][arow] = av1.x;
    As[acol + 5][arow] = av1.y;
    As[acol + 6][arow] = av1.z;
    As[acol + 7][arow] = av1.w;
    *(float4*)&Bs[brow][bcol] = bv0;
    *(float4*)&Bs[brow + 8][bcol] = bv1;
    __syncthreads();
#pragma unroll
    for (int kk = 0; kk < 16; ++kk) {
      float4 a0 = *(float4*)&As[kk][tr * 8];
      float4 a1 = *(float4*)&As[kk][tr * 8 + 4];
      float4 b0 = *(float4*)&Bs[kk][tc * 8];
      float4 b1 = *(float4*)&Bs[kk][tc * 8 + 4];
      float aa[8] = {a0.x, a0.y, a0.z, a0.w, a1.x, a1.y, a1.z, a1.w};
      float bb[8] = {b0.x, b0.y, b0.z, b0.w, b1.x, b1.y, b1.z, b1.w};
#pragma unroll
      for (int i = 0; i < 8; ++i)
#pragma unroll
        for (int j = 0; j < 8; ++j) acc[i][j] += aa[i] * bb[j];
    }
  }
#pragma unroll
  for (int i = 0; i < 8; ++i) {
    const int m = m0 + tr * 8 + i;
    const int n = n0 + tc * 8;
    float o[8];
#pragma unroll
    for (int j = 0; j < 8; ++j) o[j] = (acc[i][j] + bias[n + j]) * scale;
    if constexpr (MODE == 1) {
      uint4 u;
      u.x = (unsigned int)f2b(o[0]) | ((unsigned int)f2b(o[1]) << 16);
      u.y = (unsigned int)f2b(o[2]) | ((unsigned int)f2b(o[3]) << 16);
      u.z = (unsigned int)f2b(o[4]) | ((unsigned int)f2b(o[5]) << 16);
      u.w = (unsigned int)f2b(o[6]) | ((unsigned int)f2b(o[7]) << 16);
      *(uint4*)((unsigned short*)Cout + (size_t)m * 1024 + n) = u;
    } else if constexpr (MODE == 2) {
      unsigned short* VT = (unsigned short*)Cout;
      const int bb = m / LL;
      const int l = m - bb * LL;
#pragma unroll
      for (int j = 0; j < 8; ++j) {
        const int ch = n + j;
        VT[((size_t)(bb * HH + (ch >> 6)) * HDD + (ch & 63)) * LL + l] =
            f2b(o[j]);
      }
    } else {
      float* Cf = (float*)Cout;
      *(float4*)&Cf[(size_t)m * 1024 + n] = make_float4(o[0], o[1], o[2], o[3]);
      *(float4*)&Cf[(size_t)m * 1024 + n + 4] =
          make_float4(o[4], o[5], o[6], o[7]);
    }
  }
}

// QKV: blockIdx.z selects Q (scale 1/sqrt(64) folded in), K, V(transposed).
__global__ __launch_bounds__(256) void qkv_gemm(
    const float* __restrict__ hs, const float* __restrict__ Wq,
    const float* __restrict__ bq, const float* __restrict__ Wk,
    const float* __restrict__ bk, const float* __restrict__ Wv,
    const float* __restrict__ bv, unsigned short* __restrict__ Qb,
    unsigned short* __restrict__ Kb, unsigned short* __restrict__ VT) {
  if (blockIdx.z == 0) {
    gemm128<1>(hs, Wq, bq, Qb, 0.125f);  // 1/sqrt(HD)
  } else if (blockIdx.z == 1) {
    gemm128<1>(hs, Wk, bk, Kb, 1.0f);
  } else {
    gemm128<2>(hs, Wv, bv, VT, 1.0f);
  }
}

__global__ __launch_bounds__(256) void out_gemm(const float* __restrict__ ctx,
                                                const float* __restrict__ Wo,
                                                const float* __restrict__ bo,
                                                float* __restrict__ out) {
  gemm128<0>(ctx, Wo, bo, out, 1.0f);
}

// ---------------- fused attention: scores -> softmax -> 3x diffusion -> PV ----
// One block per (b, h, 16-row q tile). p rows live in LDS as bf16 (only LDS
// tensor). K/V fragments load directly from global (V pre-transposed).
__global__ __launch_bounds__(256) void attn_kernel(
    const unsigned short* __restrict__ Qb, const unsigned short* __restrict__ Kb,
    const unsigned short* __restrict__ VT, const int* __restrict__ mask,
    const float* __restrict__ kernel_w, float* __restrict__ ctx) {
  __shared__ __align__(16) unsigned short p_b[16][PBS];  // ~48.2 KB
  __shared__ unsigned int kvb[50];                       // packed key-valid bits
  __shared__ float red_m[4][16];
  __shared__ float red_s[4][16];

  const int t = threadIdx.x;
  const int lane = t & 63;
  const int w = t >> 6;        // wave id 0..3
  const int quad = lane >> 4;  // 0..3
  const int lc = lane & 15;
  const int b = blockIdx.z, h = blockIdx.y;
  const int q0 = blockIdx.x * 16;

  // key-valid bitmask via per-wave ballot (keys round*256 + w*64 + lane)
  if (t < 2) kvb[48 + t] = 0;
#pragma unroll
  for (int r = 0; r < 6; ++r) {
    const int idx = r * 256 + t;
    unsigned long long bal = __ballot(mask[b * LL + idx] > 0);
    if (lane == 0) {
      const int base = (r * 256 + w * 64) >> 5;
      kvb[base] = (unsigned int)bal;
      kvb[base + 1] = (unsigned int)(bal >> 32);
    }
  }
  __syncthreads();

  // ---- phase 1: scores via MFMA, K frags direct from global.
  // Wave w owns key columns g*64 + w*16 + lc; rows quad*4+r.
  const unsigned short* qp = Qb + ((size_t)(b * LL + q0 + lc)) * PP + h * HDD;
  const bf16x8 qa0 = ldb8(qp + quad * 8);
  const bf16x8 qa1 = ldb8(qp + 32 + quad * 8);
  float sc[24][4];
  const unsigned short* kpb =
      Kb + ((size_t)(b * LL + w * 16 + lc)) * PP + h * HDD;
#pragma unroll
  for (int g = 0; g < 24; ++g) {
    const unsigned short* kp = kpb + (size_t)g * 64 * PP;
    bf16x8 kb0 = ldb8(kp + quad * 8);
    bf16x8 kb1 = ldb8(kp + 32 + quad * 8);
    f32x4 acc = {0.f, 0.f, 0.f, 0.f};
    acc = __builtin_amdgcn_mfma_f32_16x16x32_bf16(qa0, kb0, acc, 0, 0, 0);
    acc = __builtin_amdgcn_mfma_f32_16x16x32_bf16(qa1, kb1, acc, 0, 0, 0);
    sc[g][0] = acc[0];
    sc[g][1] = acc[1];
    sc[g][2] = acc[2];
    sc[g][3] = acc[3];
  }

  // ---- phase 2: masked softmax (rows q = quad*4+r, cols g*64+w*16+lc)
  const int cidx = w * 16 + lc;
  const int c0 = cidx >> 5, b0 = cidx & 31;
  unsigned int mbits = 0;
#pragma unroll
  for (int g = 0; g < 24; ++g) mbits |= ((kvb[g * 2 + c0] >> b0) & 1u) << g;

  float inv[4];
  {
    float mrow[4], srow[4];
#pragma unroll
    for (int r = 0; r < 4; ++r) {
      float m = -1e30f;
#pragma unroll
      for (int g = 0; g < 24; ++g)
        if ((mbits >> g) & 1u) m = fmaxf(m, sc[g][r]);
#pragma unroll
      for (int off = 1; off < 16; off <<= 1)
        m = fmaxf(m, __shfl_xor(m, off, 64));
      mrow[r] = m;
    }
    if (lc == 0) {
#pragma unroll
      for (int r = 0; r < 4; ++r) red_m[w][quad * 4 + r] = mrow[r];
    }
    __syncthreads();
#pragma unroll
    for (int r = 0; r < 4; ++r) {
      float m = red_m[0][quad * 4 + r];
      m = fmaxf(m, red_m[1][quad * 4 + r]);
      m = fmaxf(m, red_m[2][quad * 4 + r]);
      m = fmaxf(m, red_m[3][quad * 4 + r]);
      mrow[r] = m;
    }
#pragma unroll
    for (int r = 0; r < 4; ++r) {
      float s = 0.f;
#pragma unroll
      for (int g = 0; g < 24; ++g) {
        float e = ((mbits >> g) & 1u) ? __expf(sc[g][r] - mrow[r]) : 0.f;
        sc[g][r] = e;
        s += e;
      }
#pragma unroll
      for (int off = 1; off < 16; off <<= 1) s += __shfl_xor(s, off, 64);
      srow[r] = s;
    }
    if (lc == 0) {
#pragma unroll
      for (int r = 0; r < 4; ++r) red_s[w][quad * 4 + r] = srow[r];
    }
    __syncthreads();
#pragma unroll
    for (int r = 0; r < 4; ++r) {
      float tot = red_s[0][quad * 4 + r] + red_s[1][quad * 4 + r] +
                  red_s[2][quad * 4 + r] + red_s[3][quad * 4 + r];
      inv[r] = 1.f / tot;
    }
  }
#pragma unroll
  for (int g = 0; g < 24; ++g)
#pragma unroll
    for (int r = 0; r < 4; ++r)
      p_b[quad * 4 + r][g * 64 + cidx] = f2b(sc[g][r] * inv[r]);
  __syncthreads();

  // ---- phase 3: 3 diffusion steps, fully register-resident per row.
  // Wave w owns rows 4w..4w+3; lane owns keys [lane*24, lane*24+24).
  // wr[d] multiplies p[k-d]; ref weight = softmax(kernel_w)[4-d].
  float wr[5];
  {
    float k0 = kernel_w[0], k1 = kernel_w[1], k2 = kernel_w[2],
          k3 = kernel_w[3], k4 = kernel_w[4];
    float km = fmaxf(fmaxf(fmaxf(k0, k1), fmaxf(k2, k3)), k4);
    float e0 = __expf(k0 - km), e1 = __expf(k1 - km), e2 = __expf(k2 - km),
          e3 = __expf(k3 - km), e4 = __expf(k4 - km);
    float es = e0 + e1 + e2 + e3 + e4;
    wr[0] = e4 / es;
    wr[1] = e3 / es;
    wr[2] = e2 / es;
    wr[3] = e1 / es;
    wr[4] = e0 / es;
  }
  unsigned int db;
  {
    const int w0i = (lane * 24) >> 5, sh = (lane * 24) & 31;
    unsigned long long kw2 =
        ((unsigned long long)kvb[w0i + 1] << 32) | (unsigned long long)kvb[w0i];
    db = (unsigned int)((kw2 >> sh) & 0xFFFFFFu);
  }

  for (int rr = 0; rr < 4; ++rr) {
    const int row = w * 4 + rr;
    float pf[24];
#pragma unroll
    for (int c = 0; c < 3; ++c) {
      uint4 v = *(const uint4*)&p_b[row][lane * 24 + c * 8];
      pf[c * 8 + 0] = b2f((unsigned short)(v.x & 0xFFFF));
      pf[c * 8 + 1] = b2f((unsigned short)(v.x >> 16));
      pf[c * 8 + 2] = b2f((unsigned short)(v.y & 0xFFFF));
      pf[c * 8 + 3] = b2f((unsigned short)(v.y >> 16));
      pf[c * 8 + 4] = b2f((unsigned short)(v.z & 0xFFFF));
      pf[c * 8 + 5] = b2f((unsigned short)(v.z >> 16));
      pf[c * 8 + 6] = b2f((unsigned short)(v.w & 0xFFFF));
      pf[c * 8 + 7] = b2f((unsigned short)(v.w >> 16));
    }
#pragma unroll
    for (int step = 0; step < 3; ++step) {
      float h1 = __shfl_up(pf[23], 1);
      float h2 = __shfl_up(pf[22], 1);
      float h3 = __shfl_up(pf[21], 1);
      float h4 = __shfl_up(pf[20], 1);
      if (lane == 0) h1 = h2 = h3 = h4 = 0.f;
      float ps[24];
      ps[0] = wr[0] * pf[0] + wr[1] * h1 + wr[2] * h2 + wr[3] * h3 + wr[4] * h4;
      ps[1] =
          wr[0] * pf[1] + wr[1] * pf[0] + wr[2] * h1 + wr[3] * h2 + wr[4] * h3;
      ps[2] = wr[0] * pf[2] + wr[1] * pf[1] + wr[2] * pf[0] + wr[3] * h1 +
              wr[4] * h2;
      ps[3] = wr[0] * pf[3] + wr[1] * pf[2] + wr[2] * pf[1] + wr[3] * pf[0] +
              wr[4] * h1;
#pragma unroll
      for (int i = 4; i < 24; ++i)
        ps[i] = wr[0] * pf[i] + wr[1] * pf[i - 1] + wr[2] * pf[i - 2] +
                wr[3] * pf[i - 3] + wr[4] * pf[i - 4];
      float s = 0.f;
#pragma unroll
      for (int i = 0; i < 24; ++i) {
        ps[i] = ((db >> i) & 1u) ? ps[i] : 0.f;
        s += ps[i];
      }
#pragma unroll
      for (int off = 1; off < 64; off <<= 1) s += __shfl_xor(s, off, 64);
      const float pinv = 0.02f / (s + 1e-9f);
#pragma unroll
      for (int i = 0; i < 24; ++i) pf[i] = 0.98f * pf[i] + ps[i] * pinv;
    }
#pragma unroll
    for (int c = 0; c < 3; ++c) {
      unsigned short ob[8];
#pragma unroll
      for (int j = 0; j < 8; ++j) ob[j] = f2b(pf[c * 8 + j]);
      uint4 u;
      u.x = (unsigned int)ob[0] | ((unsigned int)ob[1] << 16);
      u.y = (unsigned int)ob[2] | ((unsigned int)ob[3] << 16);
      u.z = (unsigned int)ob[4] | ((unsigned int)ob[5] << 16);
      u.w = (unsigned int)ob[6] | ((unsigned int)ob[7] << 16);
      *(uint4*)&p_b[row][lane * 24 + c * 8] = u;
    }
  }
  __syncthreads();

  // ---- phase 4: PV via MFMA, V frags direct from global VT[b][h][hd][l].
  // Wave w owns hd columns w*16 + lc.
  const unsigned short* vtp = VT + ((size_t)((b * HH + h) * HDD + cidx)) * LL;
  f32x4 oacc = {0.f, 0.f, 0.f, 0.f};
#pragma unroll
  for (int g = 0; g < 24; ++g) {
#pragma unroll
    for (int c = 0; c < 2; ++c) {
      bf16x8 pa =
          ldb8(&p_b[lc][g * 64 + c * 32 + quad * 8]);
      bf16x8 vf = ldb8(vtp + g * 64 + c * 32 + quad * 8);
      oacc = __builtin_amdgcn_mfma_f32_16x16x32_bf16(pa, vf, oacc, 0, 0, 0);
    }
  }
#pragma unroll
  for (int r = 0; r < 4; ++r)
    ctx[((size_t)(b * LL + q0 + quad * 4 + r)) * PP + h * HDD + cidx] = oacc[r];
}

extern "C" void kernel_launch(void* const* d_in, const int* in_sizes, int n_in,
                              void* d_out, int out_size, void* d_ws,
                              size_t ws_size, hipStream_t stream) {
  const float* hs = (const float*)d_in[0];
  const int* mask = (const int*)d_in[1];
  const float* Wq = (const float*)d_in[2];
  const float* bq = (const float*)d_in[3];
  const float* Wk = (const float*)d_in[4];
  const float* bk = (const float*)d_in[5];
  const float* Wv = (const float*)d_in[6];
  const float* bv = (const float*)d_in[7];
  const float* Wo = (const float*)d_in[8];
  const float* bo = (const float*)d_in[9];
  const float* kw = (const float*)d_in[10];

  const size_t NBLP = (size_t)BB * LL * PP;  // 3,145,728 elems
  unsigned short* Qb = (unsigned short*)d_ws;
  unsigned short* Kb = Qb + NBLP;
  unsigned short* VT = Kb + NBLP;  // layout [b][h][hd][l]
  float* ctx = (float*)(VT + NBLP);

  dim3 blk(256);
  qkv_gemm<<<dim3(8, 24, 3), blk, 0, stream>>>(hs, Wq, bq, Wk, bk, Wv, bv, Qb,
                                               Kb, VT);
  attn_kernel<<<dim3(96, 16, 2), blk, 0, stream>>>(Qb, Kb, VT, mask, kw, ctx);
  out_gemm<<<dim3(8, 24, 1), blk, 0, stream>>>(ctx, Wo, bo, (float*)d_out);
}

// Round 3
// 364.172 us; speedup vs baseline: 2.8243x; 1.8567x over previous
//
#include <hip/hip_runtime.h>

#define BB 2
#define LL 1536
#define DD 1024
#define HH 16
#define HDD 64
#define PP 1024
#define PBS 1544  // p_b row stride in shorts: 16B-aligned, row step = 4 banks

typedef __attribute__((ext_vector_type(8))) __bf16 bf16x8;
typedef __attribute__((ext_vector_type(4))) float f32x4;

__device__ __forceinline__ float b2f(unsigned short u) {
  unsigned int x = ((unsigned int)u) << 16;
  return __builtin_bit_cast(float, x);
}
__device__ __forceinline__ unsigned short f2b(float f) {
  unsigned int x = __builtin_bit_cast(unsigned int, f);
  unsigned int r = (x + 0x7FFFu + ((x >> 16) & 1u)) >> 16;
  return (unsigned short)r;
}
__device__ __forceinline__ bf16x8 ldb8(const unsigned short* p) {
  return __builtin_bit_cast(bf16x8, *(const uint4*)p);
}
// async global->LDS, 16B per lane; lds dst = wave-uniform base + lane*16
__device__ __forceinline__ void gl_lds16(const unsigned short* g,
                                         unsigned short* l) {
  __builtin_amdgcn_global_load_lds(
      (const __attribute__((address_space(1))) void*)g,
      (__attribute__((address_space(3))) void*)l, 16, 0, 0);
}

// ---------------- prep: cast hs to bf16 ----------------
__global__ __launch_bounds__(256) void cast_hs(const float* __restrict__ src,
                                               unsigned short* __restrict__ dst) {
  const int idx = (blockIdx.x * 256 + threadIdx.x) * 8;
  float4 a = *(const float4*)(src + idx);
  float4 b = *(const float4*)(src + idx + 4);
  uint4 u;
  u.x = (unsigned int)f2b(a.x) | ((unsigned int)f2b(a.y) << 16);
  u.y = (unsigned int)f2b(a.z) | ((unsigned int)f2b(a.w) << 16);
  u.z = (unsigned int)f2b(b.x) | ((unsigned int)f2b(b.y) << 16);
  u.w = (unsigned int)f2b(b.z) | ((unsigned int)f2b(b.w) << 16);
  *(uint4*)(dst + idx) = u;
}

// ---------------- prep: cast+transpose W[k][n] fp32 -> WT[n][k] bf16 --------
__global__ __launch_bounds__(256) void transpose_w(
    const float* __restrict__ Wq, const float* __restrict__ Wk,
    const float* __restrict__ Wv, const float* __restrict__ Wo,
    unsigned short* __restrict__ WT) {
  __shared__ float tile[64][68];
  const float* W = (blockIdx.z == 0) ? Wq
                   : (blockIdx.z == 1) ? Wk
                   : (blockIdx.z == 2) ? Wv : Wo;
  unsigned short* O = WT + (size_t)blockIdx.z * 1024 * 1024;
  const int t = threadIdx.x;
  const int r0 = blockIdx.y * 64;  // k rows
  const int c0 = blockIdx.x * 64;  // n cols
#pragma unroll
  for (int i = 0; i < 4; ++i) {
    const int row = (t >> 4) + i * 16;
    const int col = (t & 15) * 4;
    *(float4*)&tile[row][col] = *(const float4*)&W[(size_t)(r0 + row) * 1024 + c0 + col];
  }
  __syncthreads();
#pragma unroll
  for (int i = 0; i < 4; ++i) {
    const int n = (t >> 4) + i * 16;
    const int k4 = (t & 15) * 4;
    uint2 u;
    u.x = (unsigned int)f2b(tile[k4 + 0][n]) |
          ((unsigned int)f2b(tile[k4 + 1][n]) << 16);
    u.y = (unsigned int)f2b(tile[k4 + 2][n]) |
          ((unsigned int)f2b(tile[k4 + 3][n]) << 16);
    *(uint2*)&O[(size_t)(c0 + n) * 1024 + r0 + k4] = u;
  }
}

// ---------------- bf16 MFMA GEMM: C[M,1024] = A[M,1024] @ Bt[1024,1024]^T ----
// A[m][k] bf16, Bt[n][k] bf16. 128x128 tile, BK=32, 4 waves, 4x4 MFMA/wave.
// MODE 0: bf16 out *0.125 (Q). 1: bf16 out (K). 2: bf16 V-transposed
// VT[b][h][hd][l]. 3: fp32 out.
template <int MODE>
__device__ __forceinline__ void gemm_mfma_body(
    const unsigned short* __restrict__ A, const unsigned short* __restrict__ Bt,
    const float* __restrict__ bias, void* __restrict__ Cout) {
  __shared__ unsigned short As[128 * 32];
  __shared__ unsigned short Bs[128 * 32];
  const int t = threadIdx.x;
  const int lane = t & 63;
  const int w = t >> 6;
  const int quad = lane >> 4;
  const int lc = lane & 15;
  const int m0 = blockIdx.y * 128, n0 = blockIdx.x * 128;

  // staging coords: wave w covers 32 rows (2 calls of 16 rows x 32k)
  const int sr = lane >> 2;        // row within 16-row group
  const int sk = (lane & 3) * 8;   // k element offset
  const unsigned short* ga0 = A + (size_t)(m0 + w * 32 + sr) * 1024 + sk;
  const unsigned short* ga1 = ga0 + 16 * 1024;
  const unsigned short* gb0 = Bt + (size_t)(n0 + w * 32 + sr) * 1024 + sk;
  const unsigned short* gb1 = gb0 + 16 * 1024;
  unsigned short* la0 = As + w * 1024;
  unsigned short* la1 = As + w * 1024 + 512;
  unsigned short* lb0 = Bs + w * 1024;
  unsigned short* lb1 = Bs + w * 1024 + 512;

  const int mrow0 = (w >> 1) * 64, ncol0 = (w & 1) * 64;

  f32x4 acc[4][4];
#pragma unroll
  for (int i = 0; i < 4; ++i)
#pragma unroll
    for (int j = 0; j < 4; ++j) acc[i][j] = (f32x4){0.f, 0.f, 0.f, 0.f};

  for (int k0 = 0; k0 < 1024; k0 += 32) {
    __syncthreads();  // previous iter's ds_reads done before overwrite
    gl_lds16(ga0 + k0, la0);
    gl_lds16(ga1 + k0, la1);
    gl_lds16(gb0 + k0, lb0);
    gl_lds16(gb1 + k0, lb1);
    __syncthreads();  // vmcnt(0) drain: staged data visible
    bf16x8 af[4], bfr[4];
#pragma unroll
    for (int i = 0; i < 4; ++i)
      af[i] = ldb8(&As[(mrow0 + i * 16 + lc) * 32 + quad * 8]);
#pragma unroll
    for (int j = 0; j < 4; ++j)
      bfr[j] = ldb8(&Bs[(ncol0 + j * 16 + lc) * 32 + quad * 8]);
#pragma unroll
    for (int i = 0; i < 4; ++i)
#pragma unroll
      for (int j = 0; j < 4; ++j)
        acc[i][j] =
            __builtin_amdgcn_mfma_f32_16x16x32_bf16(af[i], bfr[j], acc[i][j], 0, 0, 0);
  }

#pragma unroll
  for (int i = 0; i < 4; ++i) {
    const int row0 = m0 + mrow0 + i * 16 + quad * 4;
#pragma unroll
    for (int j = 0; j < 4; ++j) {
      const int col = n0 + ncol0 + j * 16 + lc;
      const float bz = bias[col];
#pragma unroll
      for (int r = 0; r < 4; ++r) {
        float v = acc[i][j][r] + bz;
        const int row = row0 + r;
        if constexpr (MODE == 0) {
          ((unsigned short*)Cout)[(size_t)row * 1024 + col] = f2b(v * 0.125f);
        } else if constexpr (MODE == 1) {
          ((unsigned short*)Cout)[(size_t)row * 1024 + col] = f2b(v);
        } else if constexpr (MODE == 2) {
          const int bb = row / LL;
          const int l = row - bb * LL;
          ((unsigned short*)Cout)[((size_t)((bb * HH + (col >> 6)) * HDD +
                                            (col & 63))) * LL + l] = f2b(v);
        } else {
          ((float*)Cout)[(size_t)row * 1024 + col] = v;
        }
      }
    }
  }
}

__global__ __launch_bounds__(256) void qkv_gemm(
    const unsigned short* __restrict__ hsb, const unsigned short* __restrict__ WT,
    const float* __restrict__ bq, const float* __restrict__ bk,
    const float* __restrict__ bv, unsigned short* __restrict__ Qb,
    unsigned short* __restrict__ Kb, unsigned short* __restrict__ VT) {
  if (blockIdx.z == 0) {
    gemm_mfma_body<0>(hsb, WT, bq, Qb);
  } else if (blockIdx.z == 1) {
    gemm_mfma_body<1>(hsb, WT + 1024 * 1024, bk, Kb);
  } else {
    gemm_mfma_body<2>(hsb, WT + 2 * 1024 * 1024, bv, VT);
  }
}

__global__ __launch_bounds__(256) void out_gemm(
    const unsigned short* __restrict__ ctxb,
    const unsigned short* __restrict__ WoT, const float* __restrict__ bo,
    float* __restrict__ out) {
  gemm_mfma_body<3>(ctxb, WoT, bo, out);
}

// ---------------- fused attention: scores -> softmax -> 3x diffusion -> PV ----
// One block per (b, h, 16-row q tile). p rows live in LDS as bf16 (only LDS
// tensor). K/V fragments load directly from global (V pre-transposed).
__global__ __launch_bounds__(256) void attn_kernel(
    const unsigned short* __restrict__ Qb, const unsigned short* __restrict__ Kb,
    const unsigned short* __restrict__ VT, const int* __restrict__ mask,
    const float* __restrict__ kernel_w, unsigned short* __restrict__ ctxb) {
  __shared__ __align__(16) unsigned short p_b[16][PBS];  // ~48.2 KB
  __shared__ unsigned int kvb[50];                       // packed key-valid bits
  __shared__ float red_m[4][16];
  __shared__ float red_s[4][16];

  const int t = threadIdx.x;
  const int lane = t & 63;
  const int w = t >> 6;        // wave id 0..3
  const int quad = lane >> 4;  // 0..3
  const int lc = lane & 15;
  const int b = blockIdx.z, h = blockIdx.y;
  const int q0 = blockIdx.x * 16;

  // key-valid bitmask via per-wave ballot (keys round*256 + w*64 + lane)
  if (t < 2) kvb[48 + t] = 0;
#pragma unroll
  for (int r = 0; r < 6; ++r) {
    const int idx = r * 256 + t;
    unsigned long long bal = __ballot(mask[b * LL + idx] > 0);
    if (lane == 0) {
      const int base = (r * 256 + w * 64) >> 5;
      kvb[base] = (unsigned int)bal;
      kvb[base + 1] = (unsigned int)(bal >> 32);
    }
  }
  __syncthreads();

  // ---- phase 1: scores via MFMA, K frags direct from global.
  const unsigned short* qp = Qb + ((size_t)(b * LL + q0 + lc)) * PP + h * HDD;
  const bf16x8 qa0 = ldb8(qp + quad * 8);
  const bf16x8 qa1 = ldb8(qp + 32 + quad * 8);
  float sc[24][4];
  const unsigned short* kpb =
      Kb + ((size_t)(b * LL + w * 16 + lc)) * PP + h * HDD;
#pragma unroll
  for (int g = 0; g < 24; ++g) {
    const unsigned short* kp = kpb + (size_t)g * 64 * PP;
    bf16x8 kb0 = ldb8(kp + quad * 8);
    bf16x8 kb1 = ldb8(kp + 32 + quad * 8);
    f32x4 acc = {0.f, 0.f, 0.f, 0.f};
    acc = __builtin_amdgcn_mfma_f32_16x16x32_bf16(qa0, kb0, acc, 0, 0, 0);
    acc = __builtin_amdgcn_mfma_f32_16x16x32_bf16(qa1, kb1, acc, 0, 0, 0);
    sc[g][0] = acc[0];
    sc[g][1] = acc[1];
    sc[g][2] = acc[2];
    sc[g][3] = acc[3];
  }

  // ---- phase 2: masked softmax (rows q = quad*4+r, cols g*64+w*16+lc)
  const int cidx = w * 16 + lc;
  const int c0 = cidx >> 5, b0 = cidx & 31;
  unsigned int mbits = 0;
#pragma unroll
  for (int g = 0; g < 24; ++g) mbits |= ((kvb[g * 2 + c0] >> b0) & 1u) << g;

  float inv[4];
  {
    float mrow[4], srow[4];
#pragma unroll
    for (int r = 0; r < 4; ++r) {
      float m = -1e30f;
#pragma unroll
      for (int g = 0; g < 24; ++g)
        if ((mbits >> g) & 1u) m = fmaxf(m, sc[g][r]);
#pragma unroll
      for (int off = 1; off < 16; off <<= 1)
        m = fmaxf(m, __shfl_xor(m, off, 64));
      mrow[r] = m;
    }
    if (lc == 0) {
#pragma unroll
      for (int r = 0; r < 4; ++r) red_m[w][quad * 4 + r] = mrow[r];
    }
    __syncthreads();
#pragma unroll
    for (int r = 0; r < 4; ++r) {
      float m = red_m[0][quad * 4 + r];
      m = fmaxf(m, red_m[1][quad * 4 + r]);
      m = fmaxf(m, red_m[2][quad * 4 + r]);
      m = fmaxf(m, red_m[3][quad * 4 + r]);
      mrow[r] = m;
    }
#pragma unroll
    for (int r = 0; r < 4; ++r) {
      float s = 0.f;
#pragma unroll
      for (int g = 0; g < 24; ++g) {
        float e = ((mbits >> g) & 1u) ? __expf(sc[g][r] - mrow[r]) : 0.f;
        sc[g][r] = e;
        s += e;
      }
#pragma unroll
      for (int off = 1; off < 16; off <<= 1) s += __shfl_xor(s, off, 64);
      srow[r] = s;
    }
    if (lc == 0) {
#pragma unroll
      for (int r = 0; r < 4; ++r) red_s[w][quad * 4 + r] = srow[r];
    }
    __syncthreads();
#pragma unroll
    for (int r = 0; r < 4; ++r) {
      float tot = red_s[0][quad * 4 + r] + red_s[1][quad * 4 + r] +
                  red_s[2][quad * 4 + r] + red_s[3][quad * 4 + r];
      inv[r] = 1.f / tot;
    }
  }
#pragma unroll
  for (int g = 0; g < 24; ++g)
#pragma unroll
    for (int r = 0; r < 4; ++r)
      p_b[quad * 4 + r][g * 64 + cidx] = f2b(sc[g][r] * inv[r]);
  __syncthreads();

  // ---- phase 3: 3 diffusion steps, fully register-resident per row.
  float wr[5];
  {
    float k0 = kernel_w[0], k1 = kernel_w[1], k2 = kernel_w[2],
          k3 = kernel_w[3], k4 = kernel_w[4];
    float km = fmaxf(fmaxf(fmaxf(k0, k1), fmaxf(k2, k3)), k4);
    float e0 = __expf(k0 - km), e1 = __expf(k1 - km), e2 = __expf(k2 - km),
          e3 = __expf(k3 - km), e4 = __expf(k4 - km);
    float es = e0 + e1 + e2 + e3 + e4;
    wr[0] = e4 / es;
    wr[1] = e3 / es;
    wr[2] = e2 / es;
    wr[3] = e1 / es;
    wr[4] = e0 / es;
  }
  unsigned int db;
  {
    const int w0i = (lane * 24) >> 5, sh = (lane * 24) & 31;
    unsigned long long kw2 =
        ((unsigned long long)kvb[w0i + 1] << 32) | (unsigned long long)kvb[w0i];
    db = (unsigned int)((kw2 >> sh) & 0xFFFFFFu);
  }

  for (int rr = 0; rr < 4; ++rr) {
    const int row = w * 4 + rr;
    float pf[24];
#pragma unroll
    for (int c = 0; c < 3; ++c) {
      uint4 v = *(const uint4*)&p_b[row][lane * 24 + c * 8];
      pf[c * 8 + 0] = b2f((unsigned short)(v.x & 0xFFFF));
      pf[c * 8 + 1] = b2f((unsigned short)(v.x >> 16));
      pf[c * 8 + 2] = b2f((unsigned short)(v.y & 0xFFFF));
      pf[c * 8 + 3] = b2f((unsigned short)(v.y >> 16));
      pf[c * 8 + 4] = b2f((unsigned short)(v.z & 0xFFFF));
      pf[c * 8 + 5] = b2f((unsigned short)(v.z >> 16));
      pf[c * 8 + 6] = b2f((unsigned short)(v.w & 0xFFFF));
      pf[c * 8 + 7] = b2f((unsigned short)(v.w >> 16));
    }
#pragma unroll
    for (int step = 0; step < 3; ++step) {
      float h1 = __shfl_up(pf[23], 1);
      float h2 = __shfl_up(pf[22], 1);
      float h3 = __shfl_up(pf[21], 1);
      float h4 = __shfl_up(pf[20], 1);
      if (lane == 0) h1 = h2 = h3 = h4 = 0.f;
      float ps[24];
      ps[0] = wr[0] * pf[0] + wr[1] * h1 + wr[2] * h2 + wr[3] * h3 + wr[4] * h4;
      ps[1] =
          wr[0] * pf[1] + wr[1] * pf[0] + wr[2] * h1 + wr[3] * h2 + wr[4] * h3;
      ps[2] = wr[0] * pf[2] + wr[1] * pf[1] + wr[2] * pf[0] + wr[3] * h1 +
              wr[4] * h2;
      ps[3] = wr[0] * pf[3] + wr[1] * pf[2] + wr[2] * pf[1] + wr[3] * pf[0] +
              wr[4] * h1;
#pragma unroll
      for (int i = 4; i < 24; ++i)
        ps[i] = wr[0] * pf[i] + wr[1] * pf[i - 1] + wr[2] * pf[i - 2] +
                wr[3] * pf[i - 3] + wr[4] * pf[i - 4];
      float s = 0.f;
#pragma unroll
      for (int i = 0; i < 24; ++i) {
        ps[i] = ((db >> i) & 1u) ? ps[i] : 0.f;
        s += ps[i];
      }
#pragma unroll
      for (int off = 1; off < 64; off <<= 1) s += __shfl_xor(s, off, 64);
      const float pinv = 0.02f / (s + 1e-9f);
#pragma unroll
      for (int i = 0; i < 24; ++i) pf[i] = 0.98f * pf[i] + ps[i] * pinv;
    }
#pragma unroll
    for (int c = 0; c < 3; ++c) {
      unsigned short ob[8];
#pragma unroll
      for (int j = 0; j < 8; ++j) ob[j] = f2b(pf[c * 8 + j]);
      uint4 u;
      u.x = (unsigned int)ob[0] | ((unsigned int)ob[1] << 16);
      u.y = (unsigned int)ob[2] | ((unsigned int)ob[3] << 16);
      u.z = (unsigned int)ob[4] | ((unsigned int)ob[5] << 16);
      u.w = (unsigned int)ob[6] | ((unsigned int)ob[7] << 16);
      *(uint4*)&p_b[row][lane * 24 + c * 8] = u;
    }
  }
  __syncthreads();

  // ---- phase 4: PV via MFMA, V frags direct from global VT[b][h][hd][l].
  const unsigned short* vtp = VT + ((size_t)((b * HH + h) * HDD + cidx)) * LL;
  f32x4 oacc = {0.f, 0.f, 0.f, 0.f};
#pragma unroll
  for (int g = 0; g < 24; ++g) {
#pragma unroll
    for (int c = 0; c < 2; ++c) {
      bf16x8 pa = ldb8(&p_b[lc][g * 64 + c * 32 + quad * 8]);
      bf16x8 vf = ldb8(vtp + g * 64 + c * 32 + quad * 8);
      oacc = __builtin_amdgcn_mfma_f32_16x16x32_bf16(pa, vf, oacc, 0, 0, 0);
    }
  }
#pragma unroll
  for (int r = 0; r < 4; ++r)
    ctxb[((size_t)(b * LL + q0 + quad * 4 + r)) * PP + h * HDD + cidx] =
        f2b(oacc[r]);
}

extern "C" void kernel_launch(void* const* d_in, const int* in_sizes, int n_in,
                              void* d_out, int out_size, void* d_ws,
                              size_t ws_size, hipStream_t stream) {
  const float* hs = (const float*)d_in[0];
  const int* mask = (const int*)d_in[1];
  const float* Wq = (const float*)d_in[2];
  const float* bq = (const float*)d_in[3];
  const float* Wk = (const float*)d_in[4];
  const float* bk = (const float*)d_in[5];
  const float* Wv = (const float*)d_in[6];
  const float* bv = (const float*)d_in[7];
  const float* Wo = (const float*)d_in[8];
  const float* bo = (const float*)d_in[9];
  const float* kw = (const float*)d_in[10];

  const size_t NBLP = (size_t)BB * LL * PP;  // 3,145,728 elems
  unsigned short* Qb = (unsigned short*)d_ws;
  unsigned short* Kb = Qb + NBLP;
  unsigned short* VT = Kb + NBLP;   // layout [b][h][hd][l]
  unsigned short* ctxb = VT + NBLP; // bf16 ctx
  unsigned short* hsb = ctxb + NBLP;
  unsigned short* WT = hsb + NBLP;  // 4 x [1024][1024] bf16 (n-major)

  dim3 blk(256);
  cast_hs<<<dim3(1536), blk, 0, stream>>>(hs, hsb);
  transpose_w<<<dim3(16, 16, 4), blk, 0, stream>>>(Wq, Wk, Wv, Wo, WT);
  qkv_gemm<<<dim3(8, 24, 3), blk, 0, stream>>>(hsb, WT, bq, bk, bv, Qb, Kb, VT);
  attn_kernel<<<dim3(96, 16, 2), blk, 0, stream>>>(Qb, Kb, VT, mask, kw, ctxb);
  out_gemm<<<dim3(8, 24, 1), blk, 0, stream>>>(ctxb, WT + 3 * 1024 * 1024, bo,
                                               (float*)d_out);
}